// Round 6
// baseline (469.822 us; speedup 1.0000x reference)
//
#include <hip/hip_runtime.h>
#include <hip/hip_bf16.h>

#define C_ 256
#define H_ 64
#define W_ 64
#define N_ 16
#define HW_ 4096
#define IMG_ (C_ * HW_)          // 1048576 elems (fp32 image)
#define PADIMG_ (66 * 66 * 256)  // 1115136 shorts per padded NHWC image
#define WT_ELEMS_ (9 * 256 * 256)

typedef short bf16x8 __attribute__((ext_vector_type(8)));
typedef float f32x4 __attribute__((ext_vector_type(4)));

__device__ __forceinline__ unsigned short f2bf(float f) {
  __hip_bfloat16 h = __float2bfloat16(f);  // RTNE
  return *reinterpret_cast<unsigned short*>(&h);
}

__device__ __forceinline__ void gld_lds16(const void* g, void* l) {
  __builtin_amdgcn_global_load_lds(
      (const __attribute__((address_space(1))) void*)g,
      (__attribute__((address_space(3))) void*)l, 16, 0, 0);
}

// ---------------------------------------------------------------------------
// Fused x->padded-NHWC-bf16 transform + mask logits.
// Block (h, img): stages one row of all 256 channels through LDS (transpose),
// simultaneously accumulates fp64 partial logits (4 partials/pixel), then
// writes padded bf16 row + mask byte. Sign of fp64 sum is exact vs fp32 ref.
// ---------------------------------------------------------------------------
__global__ __launch_bounds__(256) void xpadmask_kernel(
    const float* __restrict__ x, const float* __restrict__ wm,
    const float* __restrict__ bm, short* __restrict__ Xp,
    unsigned char* __restrict__ mask) {
  __shared__ unsigned short lds[64 * 260];
  __shared__ float wms[256];
  __shared__ double sums[4][64];
  const int h = blockIdx.x, img = blockIdx.y;
  const int tid = threadIdx.x;
  const int wv = tid >> 6, wl = tid & 63;
  wms[tid] = wm[tid];
  __syncthreads();
  const float* xi = x + (size_t)img * IMG_ + h * 64;
  double acc = 0.0;
#pragma unroll 4
  for (int i = 0; i < 64; ++i) {
    int c = i * 4 + wv;
    float v = xi[(size_t)c * HW_ + wl];
    lds[wl * 260 + c] = f2bf(v);
    acc += (double)v * (double)wms[c];
  }
  sums[wv][wl] = acc;
  __syncthreads();
  short* Xpi = Xp + (size_t)img * PADIMG_ + ((h + 1) * 66 + 1) * 256;
#pragma unroll
  for (int j = 0; j < 16; ++j) {
    int w = j * 4 + wv;
    int c4 = wl * 4;
    uint2 d = *(const uint2*)&lds[w * 260 + c4];
    *(uint2*)&Xpi[(size_t)w * 256 + c4] = d;
  }
  if (wv == 0) {
    double t = sums[0][wl] + sums[1][wl] + sums[2][wl] + sums[3][wl] +
               (double)bm[0];
    mask[img * HW_ + h * 64 + wl] = (t > 0.0) ? 1 : 0;
  }
}

__global__ __launch_bounds__(256) void dilate_kernel(
    const unsigned char* __restrict__ mask, unsigned char* __restrict__ md) {
  int pix = blockIdx.x * 256 + threadIdx.x;
  int n = pix >> 12;
  int hw = pix & (HW_ - 1);
  int h = hw >> 6, w = hw & 63;
  int m = 0;
  for (int dy = -1; dy <= 1; dy++) {
    int hh = h + dy;
    if (hh < 0 || hh >= H_) continue;
    for (int dx = -1; dx <= 1; dx++) {
      int ww = w + dx;
      if (ww < 0 || ww >= W_) continue;
      m |= mask[n * HW_ + hh * W_ + ww];
    }
  }
  md[pix] = (unsigned char)m;
}

// ---------------------------------------------------------------------------
// Weight transform: Wt[t][k][c] = bf16(w[k][c*9+t])   (t = r*3+s)
// ---------------------------------------------------------------------------
__global__ __launch_bounds__(256) void wt_kernel(
    const float* __restrict__ w1, const float* __restrict__ w2,
    short* __restrict__ Wt1, short* __restrict__ Wt2) {
  const int k = blockIdx.x, c = threadIdx.x;
  const float* src = blockIdx.y ? w2 : w1;
  short* dst = blockIdx.y ? Wt2 : Wt1;
  const float* s = src + ((size_t)k * 256 + c) * 9;
#pragma unroll
  for (int t = 0; t < 9; ++t)
    dst[t * 65536 + k * 256 + c] = (short)f2bf(s[t]);
}

// ---------------------------------------------------------------------------
// Zero the padded halo (rows 0,65; cols 0,65) of Xp and Hp.
// ---------------------------------------------------------------------------
__global__ __launch_bounds__(128) void halo_zero(short* __restrict__ Xp,
                                                 short* __restrict__ Hp) {
  int p = blockIdx.x;  // 0..259 halo pixel id
  int r, c;
  if (p < 66) { r = 0; c = p; }
  else if (p < 132) { r = 65; c = p - 66; }
  else if (p < 196) { r = p - 131; c = 0; }
  else { r = p - 195; c = 65; }
  short* buf = blockIdx.z ? Hp : Xp;
  unsigned int* d = (unsigned int*)(buf + (size_t)blockIdx.y * PADIMG_ +
                                    (size_t)(r * 66 + c) * 256);
  d[threadIdx.x] = 0u;
}

// ---------------------------------------------------------------------------
// Implicit-GEMM 3x3 conv. Tile: 64 out-ch x 512 px (8 rows x 64 cols).
// B (pixels) staged in LDS per 32-ch K-chunk: 10 padded rows x 66 x 32ch
// (43 KB), reused by all 9 taps as LDS address offsets.
// A (weights) read DIRECTLY global->VGPR frags (Wt is 1.1 MB, L2-resident)
// -> LDS read pipe only carries B (72 b128/wave/kk < MFMA 9.3k cyc/CU/kk).
// Wave w owns output rows h0+2w, h0+2w+1; 4x8 outer product, 288 MFMA/wave/kk
// between ONE barrier pair.
// EPI 0: dstH[padded NHWC] = g ? relu(acc) : 0        (g = dilated mask)
// EPI 1: dstF[NCHW fp32]   = xres + (g ? relu(acc):0) (g = std mask)
// ---------------------------------------------------------------------------
template <int EPI>
__global__ __launch_bounds__(256, 2) void conv_mfma(
    const short* __restrict__ src, const short* __restrict__ Wt,
    const unsigned char* __restrict__ gate, const float* __restrict__ xres,
    short* __restrict__ dstH, float* __restrict__ dstF) {
  __shared__ short Bl[672 * 32];  // 43 KB: [padded px slot][kc 32]

  const int tid = threadIdx.x;
  const int lane = tid & 63, wave = tid >> 6;
  const int quad = lane >> 4, ln15 = lane & 15;
  const int ch0 = blockIdx.x * 64;
  const int h0 = blockIdx.y * 8;  // 8 output rows per block
  const int img = blockIdx.z;

  const int lr = lane >> 2;       // slot-within-16 for staging
  const int lc = (lane & 3) * 8;  // shorts offset within 32-ch chunk

  // padded rows h0..h0+9 start at padded slot h0*66
  const short* Xbase = src + (size_t)img * PADIMG_ + (size_t)(h0 * 66) * 256;
  // per-lane A frag base: row ch0+ln15, k-offset quad*8
  const short* Abase = Wt + (size_t)(ch0 + ln15) * 256 + quad * 8;

  f32x4 acc[4][8];
#pragma unroll
  for (int i = 0; i < 4; ++i)
#pragma unroll
    for (int j = 0; j < 8; ++j) acc[i][j] = {0.f, 0.f, 0.f, 0.f};

  for (int kk = 0; kk < 8; ++kk) {
    const int ko = kk * 32;
    // stage B: 660 slots (10 rows x 66), 42 insts cover 672 slots
    for (int n = wave; n < 42; n += 4) {
      gld_lds16(Xbase + (size_t)(n * 16 + lr) * 256 + ko + lc, Bl + n * 512);
    }
    __syncthreads();

#pragma unroll
    for (int t = 0; t < 9; ++t) {
      const int dy = t / 3, dx = t % 3;
      bf16x8 a[4], b[8];
#pragma unroll
      for (int i = 0; i < 4; ++i)
        a[i] = *(const bf16x8*)(Abase + (size_t)(t * 256 + i * 16) * 256 + ko);
#pragma unroll
      for (int j = 0; j < 8; ++j) {
        const int pl = (wave * 2 + (j >> 2) + dy) * 66 + (j & 3) * 16 + ln15 + dx;
        b[j] = *(const bf16x8*)&Bl[pl * 32 + quad * 8];
      }
#pragma unroll
      for (int i = 0; i < 4; ++i)
#pragma unroll
        for (int j = 0; j < 8; ++j)
          acc[i][j] = __builtin_amdgcn_mfma_f32_16x16x32_bf16(a[i], b[j],
                                                              acc[i][j], 0, 0, 0);
    }
    __syncthreads();
  }

  // Epilogue. D layout: col(pixel)=ln15, row(channel)=quad*4+reg.
  const int rbase = h0 + wave * 2;
#pragma unroll
  for (int j = 0; j < 8; ++j) {
    const int r = rbase + (j >> 2);
    const int col = (j & 3) * 16 + ln15;
    const int pidx = r * 64 + col;
    const unsigned char g = gate[img * HW_ + pidx];
#pragma unroll
    for (int i = 0; i < 4; ++i) {
      f32x4 v = acc[i][j];
      const int ch = ch0 + i * 16 + quad * 4;
      float e0 = g ? fmaxf(v[0], 0.f) : 0.f;
      float e1 = g ? fmaxf(v[1], 0.f) : 0.f;
      float e2 = g ? fmaxf(v[2], 0.f) : 0.f;
      float e3 = g ? fmaxf(v[3], 0.f) : 0.f;
      if (EPI == 0) {
        uint2 u;
        u.x = (unsigned int)f2bf(e0) | ((unsigned int)f2bf(e1) << 16);
        u.y = (unsigned int)f2bf(e2) | ((unsigned int)f2bf(e3) << 16);
        short* d = dstH + (size_t)img * PADIMG_ +
                   ((size_t)((r + 1) * 66 + (col + 1))) * 256 + ch;
        *(uint2*)d = u;
      } else {
        size_t o = (size_t)img * IMG_ + (size_t)ch * HW_ + pidx;
        dstF[o] = xres[o] + e0;
        dstF[o + HW_] = xres[o + HW_] + e1;
        dstF[o + 2 * HW_] = xres[o + 2 * HW_] + e2;
        dstF[o + 3 * HW_] = xres[o + 3 * HW_] + e3;
      }
    }
  }
}

// ---------------------------------------------------------------------------
extern "C" void kernel_launch(void* const* d_in, const int* in_sizes, int n_in,
                              void* d_out, int out_size, void* d_ws,
                              size_t ws_size, hipStream_t stream) {
  const float* x = (const float*)d_in[0];
  const float* w1 = (const float*)d_in[1];
  const float* w2 = (const float*)d_in[2];
  const float* wmask = (const float*)d_in[3];
  const float* bmask = (const float*)d_in[4];
  float* out = (float*)d_out;

  char* ws = (char*)d_ws;
  unsigned char* mask = (unsigned char*)ws;          // 64 KB
  unsigned char* md = (unsigned char*)(ws + 65536);  // 64 KB
  short* Wt1 = (short*)(ws + 131072);                // 1.125 MiB
  short* Wt2 = Wt1 + WT_ELEMS_;                      // 1.125 MiB
  short* Xp = (short*)(ws + 2490368);

  const size_t fixed = 2490368;
  const size_t tailpad = 32768;  // B-stage overshoot pad past last image
  const size_t per_img = 2 * (size_t)PADIMG_ * 2;  // Xp + Hp bytes per image
  int B = (ws_size > fixed + tailpad)
              ? (int)((ws_size - fixed - tailpad) / per_img) : 0;
  if (B > N_) B = N_;
  if (B < 1) B = 1;
  short* Hp = Xp + (size_t)B * PADIMG_;

  wt_kernel<<<dim3(256, 2), 256, 0, stream>>>(w1, w2, Wt1, Wt2);
  halo_zero<<<dim3(260, B, 2), 128, 0, stream>>>(Xp, Hp);

  for (int n0 = 0; n0 < N_; n0 += B) {
    const int nb = (N_ - n0 < B) ? (N_ - n0) : B;
    xpadmask_kernel<<<dim3(64, nb), 256, 0, stream>>>(
        x + (size_t)n0 * IMG_, wmask, bmask, Xp, mask + n0 * HW_);
    dilate_kernel<<<nb * HW_ / 256, 256, 0, stream>>>(mask + n0 * HW_,
                                                      md + n0 * HW_);
    conv_mfma<0><<<dim3(4, 8, nb), 256, 0, stream>>>(
        Xp, Wt1, md + n0 * HW_, nullptr, Hp, nullptr);
    conv_mfma<1><<<dim3(4, 8, nb), 256, 0, stream>>>(
        Hp, Wt2, mask + n0 * HW_, x + (size_t)n0 * IMG_, nullptr,
        out + (size_t)n0 * IMG_);
  }
}

// Round 7
// 306.735 us; speedup vs baseline: 1.5317x; 1.5317x over previous
//
#include <hip/hip_runtime.h>
#include <hip/hip_bf16.h>

#define C_ 256
#define H_ 64
#define W_ 64
#define N_ 16
#define HW_ 4096
#define IMG_ (C_ * HW_)          // 1048576 elems (fp32 image)
#define PADIMG_ (66 * 66 * 256)  // 1115136 shorts per padded NHWC image
#define WT_ELEMS_ (9 * 256 * 256)

typedef short bf16x8 __attribute__((ext_vector_type(8)));
typedef float f32x4 __attribute__((ext_vector_type(4)));

__device__ __forceinline__ unsigned short f2bf(float f) {
  __hip_bfloat16 h = __float2bfloat16(f);  // RTNE
  return *reinterpret_cast<unsigned short*>(&h);
}

__device__ __forceinline__ void gld_lds16(const void* g, void* l) {
  __builtin_amdgcn_global_load_lds(
      (const __attribute__((address_space(1))) void*)g,
      (__attribute__((address_space(3))) void*)l, 16, 0, 0);
}

// ---------------------------------------------------------------------------
// Fused x->padded-NHWC-bf16 transform + mask logits (fp64, sign-exact).
// ---------------------------------------------------------------------------
__global__ __launch_bounds__(256) void xpadmask_kernel(
    const float* __restrict__ x, const float* __restrict__ wm,
    const float* __restrict__ bm, short* __restrict__ Xp,
    unsigned char* __restrict__ mask) {
  __shared__ unsigned short lds[64 * 260];
  __shared__ float wms[256];
  __shared__ double sums[4][64];
  const int h = blockIdx.x, img = blockIdx.y;
  const int tid = threadIdx.x;
  const int wv = tid >> 6, wl = tid & 63;
  wms[tid] = wm[tid];
  __syncthreads();
  const float* xi = x + (size_t)img * IMG_ + h * 64;
  double a0 = 0.0, a1 = 0.0, a2 = 0.0, a3 = 0.0;
#pragma unroll 4
  for (int i = 0; i < 16; ++i) {
#pragma unroll
    for (int u = 0; u < 4; ++u) {
      int c = (i * 4 + u) * 4 + wv;
      float v = xi[(size_t)c * HW_ + wl];
      lds[wl * 260 + c] = f2bf(v);
      double p = (double)v * (double)wms[c];
      if (u == 0) a0 += p;
      else if (u == 1) a1 += p;
      else if (u == 2) a2 += p;
      else a3 += p;
    }
  }
  sums[wv][wl] = (a0 + a1) + (a2 + a3);
  __syncthreads();
  short* Xpi = Xp + (size_t)img * PADIMG_ + ((h + 1) * 66 + 1) * 256;
#pragma unroll
  for (int j = 0; j < 16; ++j) {
    int w = j * 4 + wv;
    int c4 = wl * 4;
    uint2 d = *(const uint2*)&lds[w * 260 + c4];
    *(uint2*)&Xpi[(size_t)w * 256 + c4] = d;
  }
  if (wv == 0) {
    double t = sums[0][wl] + sums[1][wl] + sums[2][wl] + sums[3][wl] +
               (double)bm[0];
    mask[img * HW_ + h * 64 + wl] = (t > 0.0) ? 1 : 0;
  }
}

__global__ __launch_bounds__(256) void dilate_kernel(
    const unsigned char* __restrict__ mask, unsigned char* __restrict__ md) {
  int pix = blockIdx.x * 256 + threadIdx.x;
  int n = pix >> 12;
  int hw = pix & (HW_ - 1);
  int h = hw >> 6, w = hw & 63;
  int m = 0;
  for (int dy = -1; dy <= 1; dy++) {
    int hh = h + dy;
    if (hh < 0 || hh >= H_) continue;
    for (int dx = -1; dx <= 1; dx++) {
      int ww = w + dx;
      if (ww < 0 || ww >= W_) continue;
      m |= mask[n * HW_ + hh * W_ + ww];
    }
  }
  md[pix] = (unsigned char)m;
}

// ---------------------------------------------------------------------------
// Weight transform: Wt[t][k][c] = bf16(w[k][c*9+t])   (t = r*3+s)
// ---------------------------------------------------------------------------
__global__ __launch_bounds__(256) void wt_kernel(
    const float* __restrict__ w1, const float* __restrict__ w2,
    short* __restrict__ Wt1, short* __restrict__ Wt2) {
  const int k = blockIdx.x, c = threadIdx.x;
  const float* src = blockIdx.y ? w2 : w1;
  short* dst = blockIdx.y ? Wt2 : Wt1;
  const float* s = src + ((size_t)k * 256 + c) * 9;
#pragma unroll
  for (int t = 0; t < 9; ++t)
    dst[t * 65536 + k * 256 + c] = (short)f2bf(s[t]);
}

// ---------------------------------------------------------------------------
// Zero the padded halo (rows 0,65; cols 0,65) of Xp and Hp.
// ---------------------------------------------------------------------------
__global__ __launch_bounds__(128) void halo_zero(short* __restrict__ Xp,
                                                 short* __restrict__ Hp) {
  int p = blockIdx.x;  // 0..259 halo pixel id
  int r, c;
  if (p < 66) { r = 0; c = p; }
  else if (p < 132) { r = 65; c = p - 66; }
  else if (p < 196) { r = p - 131; c = 0; }
  else { r = p - 195; c = 65; }
  short* buf = blockIdx.z ? Hp : Xp;
  unsigned int* d = (unsigned int*)(buf + (size_t)blockIdx.y * PADIMG_ +
                                    (size_t)(r * 66 + c) * 256);
  d[threadIdx.x] = 0u;
}

// ---------------------------------------------------------------------------
// Implicit-GEMM 3x3 conv. Tile: 64 out-ch x 512 px (8 rows x 64 cols).
// Per 32-ch K-chunk: Bl staged once (10 padded rows x 66, 43 KB) and reused
// by all 9 taps; A staged in 3 dy-phases of 3 taps (12 KB) to fit 64 KB LDS.
// Wave w owns rows h0+2w..h0+2w+1; 4x8 outer product -> 0.375 LDS-read/MFMA.
// A returns to LDS (round-6 lesson: point-of-use global loads stall vmcnt).
// EPI 0: dstH[padded NHWC] = g ? relu(acc) : 0        (g = dilated mask)
// EPI 1: dstF[NCHW fp32]   = xres + (g ? relu(acc):0) (g = std mask)
// ---------------------------------------------------------------------------
template <int EPI>
__global__ __launch_bounds__(256, 2) void conv_mfma(
    const short* __restrict__ src, const short* __restrict__ Wt,
    const unsigned char* __restrict__ gate, const float* __restrict__ xres,
    short* __restrict__ dstH, float* __restrict__ dstF) {
  __shared__ short Wl[3 * 64 * 32];  // 12 KB: [tap-in-phase][out-ch 64][kc 32]
  __shared__ short Bl[672 * 32];     // 43 KB: [padded px slot][kc 32]

  const int tid = threadIdx.x;
  const int lane = tid & 63, wave = tid >> 6;
  const int quad = lane >> 4, ln15 = lane & 15;
  const int ch0 = blockIdx.x * 64;
  const int h0 = blockIdx.y * 8;  // 8 output rows per block
  const int img = blockIdx.z;

  const int lr = lane >> 2;       // slot-within-16 for staging
  const int lc = (lane & 3) * 8;  // shorts offset within 32-ch chunk

  // padded rows h0..h0+9 start at padded slot h0*66
  const short* Xbase = src + (size_t)img * PADIMG_ + (size_t)(h0 * 66) * 256;
  const short* Wbase = Wt + (size_t)(ch0 + wave * 16 + lr) * 256 + lc;

  f32x4 acc[4][8];
#pragma unroll
  for (int i = 0; i < 4; ++i)
#pragma unroll
    for (int j = 0; j < 8; ++j) acc[i][j] = {0.f, 0.f, 0.f, 0.f};

  for (int kk = 0; kk < 8; ++kk) {
    const int ko = kk * 32;
    // stage B: 660 slots (10 rows x 66), 42 insts cover 672 slots
    for (int n = wave; n < 42; n += 4) {
      gld_lds16(Xbase + (size_t)(n * 16 + lr) * 256 + ko + lc, Bl + n * 512);
    }
    // stage A phase dy=0 (taps 0..2)
#pragma unroll
    for (int tl = 0; tl < 3; ++tl)
      gld_lds16(Wbase + (size_t)tl * 65536 + ko,
                Wl + (tl * 64 + wave * 16) * 32);
    __syncthreads();

#pragma unroll
    for (int dy = 0; dy < 3; ++dy) {
      bf16x8 a[4], b[8];
#pragma unroll
      for (int tl = 0; tl < 3; ++tl) {
#pragma unroll
        for (int i = 0; i < 4; ++i)
          a[i] = *(const bf16x8*)&Wl[(tl * 64 + i * 16 + ln15) * 32 + quad * 8];
#pragma unroll
        for (int j = 0; j < 8; ++j) {
          const int pl =
              (wave * 2 + (j >> 2) + dy) * 66 + (j & 3) * 16 + ln15 + tl;
          b[j] = *(const bf16x8*)&Bl[pl * 32 + quad * 8];
        }
#pragma unroll
        for (int i = 0; i < 4; ++i)
#pragma unroll
          for (int j = 0; j < 8; ++j)
            acc[i][j] = __builtin_amdgcn_mfma_f32_16x16x32_bf16(
                a[i], b[j], acc[i][j], 0, 0, 0);
      }
      __syncthreads();  // phase compute done; Wl free (also guards Bl at kk end)
      if (dy < 2) {
#pragma unroll
        for (int tl = 0; tl < 3; ++tl)
          gld_lds16(Wbase + (size_t)((dy + 1) * 3 + tl) * 65536 + ko,
                    Wl + (tl * 64 + wave * 16) * 32);
        __syncthreads();
      }
    }
  }

  // Epilogue. D layout: col(pixel)=ln15, row(channel)=quad*4+reg.
  const int rbase = h0 + wave * 2;
#pragma unroll
  for (int j = 0; j < 8; ++j) {
    const int r = rbase + (j >> 2);
    const int col = (j & 3) * 16 + ln15;
    const int pidx = r * 64 + col;
    const unsigned char g = gate[img * HW_ + pidx];
#pragma unroll
    for (int i = 0; i < 4; ++i) {
      f32x4 v = acc[i][j];
      const int ch = ch0 + i * 16 + quad * 4;
      float e0 = g ? fmaxf(v[0], 0.f) : 0.f;
      float e1 = g ? fmaxf(v[1], 0.f) : 0.f;
      float e2 = g ? fmaxf(v[2], 0.f) : 0.f;
      float e3 = g ? fmaxf(v[3], 0.f) : 0.f;
      if (EPI == 0) {
        uint2 u;
        u.x = (unsigned int)f2bf(e0) | ((unsigned int)f2bf(e1) << 16);
        u.y = (unsigned int)f2bf(e2) | ((unsigned int)f2bf(e3) << 16);
        short* d = dstH + (size_t)img * PADIMG_ +
                   ((size_t)((r + 1) * 66 + (col + 1))) * 256 + ch;
        *(uint2*)d = u;
      } else {
        size_t o = (size_t)img * IMG_ + (size_t)ch * HW_ + pidx;
        dstF[o] = xres[o] + e0;
        dstF[o + HW_] = xres[o + HW_] + e1;
        dstF[o + 2 * HW_] = xres[o + 2 * HW_] + e2;
        dstF[o + 3 * HW_] = xres[o + 3 * HW_] + e3;
      }
    }
  }
}

// ---------------------------------------------------------------------------
extern "C" void kernel_launch(void* const* d_in, const int* in_sizes, int n_in,
                              void* d_out, int out_size, void* d_ws,
                              size_t ws_size, hipStream_t stream) {
  const float* x = (const float*)d_in[0];
  const float* w1 = (const float*)d_in[1];
  const float* w2 = (const float*)d_in[2];
  const float* wmask = (const float*)d_in[3];
  const float* bmask = (const float*)d_in[4];
  float* out = (float*)d_out;

  char* ws = (char*)d_ws;
  unsigned char* mask = (unsigned char*)ws;          // 64 KB
  unsigned char* md = (unsigned char*)(ws + 65536);  // 64 KB
  short* Wt1 = (short*)(ws + 131072);                // 1.125 MiB
  short* Wt2 = Wt1 + WT_ELEMS_;                      // 1.125 MiB
  short* Xp = (short*)(ws + 2490368);

  const size_t fixed = 2490368;
  const size_t tailpad = 32768;  // B-stage overshoot pad past last image
  const size_t per_img = 2 * (size_t)PADIMG_ * 2;  // Xp + Hp bytes per image
  int B = (ws_size > fixed + tailpad)
              ? (int)((ws_size - fixed - tailpad) / per_img) : 0;
  if (B > N_) B = N_;
  if (B < 1) B = 1;
  short* Hp = Xp + (size_t)B * PADIMG_;

  wt_kernel<<<dim3(256, 2), 256, 0, stream>>>(w1, w2, Wt1, Wt2);
  halo_zero<<<dim3(260, B, 2), 128, 0, stream>>>(Xp, Hp);

  for (int n0 = 0; n0 < N_; n0 += B) {
    const int nb = (N_ - n0 < B) ? (N_ - n0) : B;
    xpadmask_kernel<<<dim3(64, nb), 256, 0, stream>>>(
        x + (size_t)n0 * IMG_, wmask, bmask, Xp, mask + n0 * HW_);
    dilate_kernel<<<nb * HW_ / 256, 256, 0, stream>>>(mask + n0 * HW_,
                                                      md + n0 * HW_);
    conv_mfma<0><<<dim3(4, 8, nb), 256, 0, stream>>>(
        Xp, Wt1, md + n0 * HW_, nullptr, Hp, nullptr);
    conv_mfma<1><<<dim3(4, 8, nb), 256, 0, stream>>>(
        Hp, Wt2, mask + n0 * HW_, x + (size_t)n0 * IMG_, nullptr,
        out + (size_t)n0 * IMG_);
  }
}